// Round 4
// baseline (685.097 us; speedup 1.0000x reference)
//
#include <hip/hip_runtime.h>
#include <stdint.h>

#define DEV __device__ __forceinline__

typedef float f32x4 __attribute__((ext_vector_type(4)));

constexpr int nB = 64;
constexpr int nL = 1024;
constexpr int nD = 2048;
constexpr int nH = 128;

constexpr int NT = 16;          // L tiles for mean
constexpr int LT = nL / NT;     // 64 rows per tile

constexpr size_t X_ELEMS = (size_t)nB * (size_t)nL * (size_t)nD;  // 134217728

// ---------- math helpers (match JAX/XLA fp32 semantics closely) ----------
DEV float gelu_f(float x) {
  return 0.5f * x * (1.0f + erff(x * 0.7071067811865476f));
}
DEV float gelu_grad_f(float x) {
  return 0.5f * (1.0f + erff(x * 0.7071067811865476f))
       + x * 0.3989422804014327f * expf(-0.5f * x * x);
}
DEV float sigmoid_f(float x) { return 1.0f / (1.0f + expf(-x)); }

DEV uint32_t rotl32(uint32_t v, int r) { return (v << r) | (v >> (32 - r)); }

// Threefry-2x32 with key (0,1)  == jax.random.key(1)
DEV void threefry_key01(uint32_t& x0, uint32_t& x1) {
  const uint32_t ks0 = 0u, ks1 = 1u, ks2 = 0x1BD11BDAu ^ 0u ^ 1u;
  x0 += ks0; x1 += ks1;
#define TF_RND(r) { x0 += x1; x1 = rotl32(x1, (r)); x1 ^= x0; }
  TF_RND(13) TF_RND(15) TF_RND(26) TF_RND(6)
  x0 += ks1; x1 += ks2 + 1u;
  TF_RND(17) TF_RND(29) TF_RND(16) TF_RND(24)
  x0 += ks2; x1 += ks0 + 2u;
  TF_RND(13) TF_RND(15) TF_RND(26) TF_RND(6)
  x0 += ks0; x1 += ks1 + 3u;
  TF_RND(17) TF_RND(29) TF_RND(16) TF_RND(24)
  x0 += ks1; x1 += ks2 + 4u;
  TF_RND(13) TF_RND(15) TF_RND(26) TF_RND(6)
  x0 += ks2; x1 += ks0 + 5u;
#undef TF_RND
}

// XLA ErfInv32 (Giles single-precision polynomial)
DEV float erfinv_f32(float x) {
  float w = -log1pf(-x * x);
  float p;
  if (w < 5.0f) {
    w -= 2.5f;
    p = 2.81022636e-08f;
    p = fmaf(p, w, 3.43273939e-07f);
    p = fmaf(p, w, -3.5233877e-06f);
    p = fmaf(p, w, -4.39150654e-06f);
    p = fmaf(p, w, 0.00021858087f);
    p = fmaf(p, w, -0.00125372503f);
    p = fmaf(p, w, -0.00417768164f);
    p = fmaf(p, w, 0.246640727f);
    p = fmaf(p, w, 1.50140941f);
  } else {
    w = sqrtf(w) - 3.0f;
    p = -0.000200214257f;
    p = fmaf(p, w, 0.000100950558f);
    p = fmaf(p, w, 0.00134934322f);
    p = fmaf(p, w, -0.00367342844f);
    p = fmaf(p, w, 0.00573950773f);
    p = fmaf(p, w, -0.0076224613f);
    p = fmaf(p, w, 0.00943887047f);
    p = fmaf(p, w, 1.00167406f);
    p = fmaf(p, w, 2.83297682f);
  }
  return p * x;
}

// jax.random.normal(key(1), (64,2048), f32), element i of row-major flat array
DEV float jax_normal_key1(int i) {
  const uint32_t j = (uint32_t)(i & 0xFFFF);
  uint32_t x0 = j, x1 = j + 65536u;
  threefry_key01(x0, x1);
  const uint32_t bits = (i < 65536) ? x0 : x1;
  const float u01 = __uint_as_float((bits >> 9) | 0x3F800000u) - 1.0f;
  const float lo = __uint_as_float(0xBF7FFFFFu);   // nextafter(-1,0)
  float v = u01 * 2.0f + lo;
  v = fmaxf(lo, v);
  return 1.4142135623730951f * erfinv_f32(v);
}

// ---------- K0: W1 [2048,128] -> W1T [128,2048] ----------
__global__ __launch_bounds__(256) void k_transpose(
    const float* __restrict__ W1, float* __restrict__ W1T)
{
  __shared__ float tile[64][65];
  const int bd = blockIdx.x;   // 0..31  (d block of 64)
  const int bh = blockIdx.y;   // 0..1   (h block of 64)
  const int t = threadIdx.x;
  const int j = t & 63;
  const int i0 = (t >> 6) * 16;
  for (int ii = 0; ii < 16; ++ii) {
    const int i = i0 + ii;
    tile[i][j] = W1[(size_t)(bd * 64 + i) * nH + bh * 64 + j];
  }
  __syncthreads();
  for (int ii = 0; ii < 16; ++ii) {
    const int i = i0 + ii;     // i = h-local, j = d-local
    W1T[(size_t)(bh * 64 + i) * nD + bd * 64 + j] = tile[j][i];
  }
}

// ---------- zero helper (graph-capture safe) ----------
__global__ __launch_bounds__(256) void k_zero(float* __restrict__ p, int n) {
  const int i = blockIdx.x * 256 + threadIdx.x;
  if (i < n) p[i] = 0.f;
}

// ---------- THE fused kernel ----------
// blocks [0,1024): copy x->out (nontemporal) + per-tile partial mean,
//                  then release-increment ctr[batch].
// blocks [1024,1088): acquire-spin until ctr[b]==16, then run the WHOLE
//                  10-step PGD for batch b with xa/pooled in LDS.
// Capacity: <=8 blocks/CU * 256 CUs >> 64 spinners -> no deadlock.
__global__ __launch_bounds__(256) void k_fused(
    const float* __restrict__ x, float* __restrict__ out,
    const float* __restrict__ W1, const float* __restrict__ W1T,
    const float* __restrict__ b1, const float* __restrict__ W2,
    const float* __restrict__ b2, float* __restrict__ pmean,
    float* __restrict__ scores, int* __restrict__ ctr)
{
  __shared__ float xaS[nD];
  __shared__ float pooledS[nD];
  __shared__ float redS[4][nH];
  __shared__ float dz1S[nH];
  __shared__ float red2[2];

  const int t = threadIdx.x;

  if (blockIdx.x < (unsigned)(nB * NT)) {
    // ================= copy + partial mean =================
    const int blk = blockIdx.x;            // = b*16 + tile
    const size_t base = (size_t)blk * LT * nD;
    const size_t o0 = (size_t)4 * t;       // d in [0,1024)
    const size_t o1 = 1024 + (size_t)4 * t;
    f32x4 a0 = {0.f, 0.f, 0.f, 0.f};
    f32x4 a1 = {0.f, 0.f, 0.f, 0.f};
    for (int l = 0; l < LT; ++l) {
      const size_t r = base + (size_t)l * nD;
      const f32x4 v0 = __builtin_nontemporal_load(
          reinterpret_cast<const f32x4*>(x + r + o0));
      const f32x4 v1 = __builtin_nontemporal_load(
          reinterpret_cast<const f32x4*>(x + r + o1));
      __builtin_nontemporal_store(v0, reinterpret_cast<f32x4*>(out + r + o0));
      __builtin_nontemporal_store(v1, reinterpret_cast<f32x4*>(out + r + o1));
      a0 += v0;
      a1 += v1;
    }
    float* pm = pmean + (size_t)blk * nD;
    *reinterpret_cast<f32x4*>(pm + o0) = a0;   // normal stores: consumed soon
    *reinterpret_cast<f32x4*>(pm + o1) = a1;
    __threadfence();        // release my writes to device scope
    __syncthreads();        // all threads' writes issued+fenced
    if (t == 0)
      __hip_atomic_fetch_add(&ctr[blk >> 4], 1, __ATOMIC_RELEASE,
                             __HIP_MEMORY_SCOPE_AGENT);
    return;
  }

  // ================= PGD block (one batch) =================
  const int b = blockIdx.x - nB * NT;      // 0..63

  // acquire-spin until this batch's 16 tile partials are published
  while (__hip_atomic_load(&ctr[b], __ATOMIC_ACQUIRE,
                           __HIP_MEMORY_SCOPE_AGENT) < NT) {}
  __syncthreads();

  // pooled reduce (8 d per thread) + threefry noise -> xa0
  const int d0 = t * 8;
  {
    f32x4 s0 = {0.f, 0.f, 0.f, 0.f};
    f32x4 s1 = {0.f, 0.f, 0.f, 0.f};
    for (int nt2 = 0; nt2 < NT; ++nt2) {
      const f32x4* pm = reinterpret_cast<const f32x4*>(
          pmean + ((size_t)(b * NT + nt2)) * nD + d0);
      s0 += pm[0];
      s1 += pm[1];
    }
    const float sc = 1.0f / nL;
    float pl[8] = { s0.x*sc, s0.y*sc, s0.z*sc, s0.w*sc,
                    s1.x*sc, s1.y*sc, s1.z*sc, s1.w*sc };
    const int i0 = b * nD + d0;
    #pragma unroll
    for (int i = 0; i < 8; ++i) {
      pooledS[d0 + i] = pl[i];
      xaS[d0 + i] = pl[i] + 0.01f * jax_normal_key1(i0 + i);
    }
  }

  const float b1t = (t < nH) ? b1[t] : 0.f;
  const float w2t = (t < nH) ? W2[t] : 0.f;
  const float b2s = b2[0];

  __syncthreads();

  const int hp = t & 63;        // h-pair index: handles h = 2hp, 2hp+1
  const int q  = t >> 6;        // d quarter 0..3 (512 d each)
  const float2* __restrict__ w1q =
      reinterpret_cast<const float2*>(W1) + (size_t)(q * 512) * 64 + hp;

  float sig_last = 0.f;
  for (int it = 0; it <= 10; ++it) {
    // ---- forward: z1 partials; wave reads 512B/instr of W1 ----
    float accx = 0.f, accy = 0.f;
    #pragma unroll 8
    for (int dd = 0; dd < 512; ++dd) {
      const float xv = xaS[q * 512 + dd];         // LDS broadcast
      const float2 w = w1q[(size_t)dd * 64];
      accx = fmaf(xv, w.x, accx);
      accy = fmaf(xv, w.y, accy);
    }
    *reinterpret_cast<float2*>(&redS[q][2 * hp]) = make_float2(accx, accy);
    __syncthreads();

    float z1 = 0.f;
    if (t < nH) {
      z1 = redS[0][t] + redS[1][t] + redS[2][t] + redS[3][t] + b1t;
      float part = gelu_f(z1) * w2t;
      #pragma unroll
      for (int m = 1; m <= 32; m <<= 1) part += __shfl_xor(part, m, 64);
      if ((t & 63) == 0) red2[t >> 6] = part;
    }
    __syncthreads();

    const float sig = sigmoid_f(red2[0] + red2[1] + b2s);
    if (it == 10) { sig_last = sig; break; }

    if (t < nH) dz1S[t] = sig * (1.f - sig) * w2t * gelu_grad_f(z1);
    __syncthreads();

    // ---- backward: g = W1 . dz1 via W1T; 2KB/instr full width ----
    float g0=0.f,g1=0.f,g2=0.f,g3=0.f,g4=0.f,g5=0.f,g6=0.f,g7=0.f;
    #pragma unroll 4
    for (int h = 0; h < nH; ++h) {
      const float dz = dz1S[h];                   // LDS broadcast
      const f32x4* wr = reinterpret_cast<const f32x4*>(
          W1T + (size_t)h * nD + d0);
      const f32x4 a = wr[0], c = wr[1];
      g0 = fmaf(dz, a.x, g0); g1 = fmaf(dz, a.y, g1);
      g2 = fmaf(dz, a.z, g2); g3 = fmaf(dz, a.w, g3);
      g4 = fmaf(dz, c.x, g4); g5 = fmaf(dz, c.y, g5);
      g6 = fmaf(dz, c.z, g6); g7 = fmaf(dz, c.w, g7);
    }
    float g[8] = {g0,g1,g2,g3,g4,g5,g6,g7};
    #pragma unroll
    for (int i = 0; i < 8; ++i) {
      const float gv = g[i];
      const float sg = (gv > 0.f) ? 1.f : ((gv < 0.f) ? -1.f : 0.f);
      const float pl = pooledS[d0 + i];
      float dlt = (xaS[d0 + i] - 0.01f * sg) - pl;
      dlt = fminf(fmaxf(dlt, -0.2f), 0.2f);
      xaS[d0 + i] = pl + dlt;
    }
    __syncthreads();
  }

  if (t == 0) scores[b] = sig_last;
}

// ---------- fallback (small ws): round-2 proven path ----------
__global__ __launch_bounds__(256) void k_copy_mean_atomic(
    const float* __restrict__ x, float* __restrict__ out,
    float* __restrict__ pooled)
{
  const int blk = blockIdx.x;
  const int b = blk >> 4;
  const int t = threadIdx.x;
  const size_t base = (size_t)blk * LT * nD;
  const size_t o0 = (size_t)4 * t;
  const size_t o1 = 1024 + (size_t)4 * t;
  float4 a0 = make_float4(0.f,0.f,0.f,0.f);
  float4 a1 = make_float4(0.f,0.f,0.f,0.f);
  for (int l = 0; l < LT; ++l) {
    const size_t r = base + (size_t)l * nD;
    const float4 v0 = *reinterpret_cast<const float4*>(x + r + o0);
    const float4 v1 = *reinterpret_cast<const float4*>(x + r + o1);
    *reinterpret_cast<float4*>(out + r + o0) = v0;
    *reinterpret_cast<float4*>(out + r + o1) = v1;
    a0.x += v0.x; a0.y += v0.y; a0.z += v0.z; a0.w += v0.w;
    a1.x += v1.x; a1.y += v1.y; a1.z += v1.z; a1.w += v1.w;
  }
  float* pp = pooled + (size_t)b * nD;
  const float sc = 1.0f / nL;
  atomicAdd(&pp[o0+0], a0.x*sc); atomicAdd(&pp[o0+1], a0.y*sc);
  atomicAdd(&pp[o0+2], a0.z*sc); atomicAdd(&pp[o0+3], a0.w*sc);
  atomicAdd(&pp[o1+0], a1.x*sc); atomicAdd(&pp[o1+1], a1.y*sc);
  atomicAdd(&pp[o1+2], a1.z*sc); atomicAdd(&pp[o1+3], a1.w*sc);
}

__global__ __launch_bounds__(1024) void k_pgd(
    const float* __restrict__ W1, const float* __restrict__ W1T,
    const float* __restrict__ b1, const float* __restrict__ W2,
    const float* __restrict__ b2, const float* __restrict__ pooledG,
    float* __restrict__ scores)
{
  __shared__ float xaS[nD];
  __shared__ float pooledS[nD];
  __shared__ float red[8][nH];
  __shared__ float dz1S[nH];
  __shared__ float red2[2];

  const int t = threadIdx.x;
  const int b = blockIdx.x;
  const int h = t & (nH - 1);
  const int dq = t >> 7;

  float2 pl = *reinterpret_cast<const float2*>(&pooledG[(size_t)b * nD + 2*t]);
  pooledS[2*t] = pl.x; pooledS[2*t+1] = pl.y;
  const int i0 = b * nD + 2 * t;
  xaS[2*t]   = pl.x + 0.01f * jax_normal_key1(i0);
  xaS[2*t+1] = pl.y + 0.01f * jax_normal_key1(i0 + 1);

  const float b1t = (t < nH) ? b1[t] : 0.f;
  const float w2t = (t < nH) ? W2[t] : 0.f;
  const float b2s = b2[0];
  const float2* __restrict__ w1t2 = reinterpret_cast<const float2*>(W1T);
  __syncthreads();

  float sig_last = 0.f;
  for (int it = 0; it <= 10; ++it) {
    float acc = 0.f;
    const float* __restrict__ w1p = W1 + (size_t)(dq * 256) * nH + h;
    #pragma unroll 8
    for (int d = 0; d < 256; ++d)
      acc = fmaf(xaS[dq * 256 + d], w1p[(size_t)d * nH], acc);
    red[dq][h] = acc;
    __syncthreads();

    float z1 = 0.f;
    if (t < nH) {
      #pragma unroll
      for (int q2 = 0; q2 < 8; ++q2) z1 += red[q2][t];
      z1 += b1t;
      float part = gelu_f(z1) * w2t;
      #pragma unroll
      for (int m = 1; m <= 32; m <<= 1) part += __shfl_xor(part, m, 64);
      if ((t & 63) == 0) red2[t >> 6] = part;
    }
    __syncthreads();

    const float sig = sigmoid_f(red2[0] + red2[1] + b2s);
    if (it == 10) { sig_last = sig; break; }
    if (t < nH) dz1S[t] = sig * (1.f - sig) * w2t * gelu_grad_f(z1);
    __syncthreads();

    float gx = 0.f, gy = 0.f;
    #pragma unroll 8
    for (int hh = 0; hh < nH; ++hh) {
      const float dz = dz1S[hh];
      const float2 w = w1t2[(size_t)hh * (nD / 2) + t];
      gx = fmaf(dz, w.x, gx);
      gy = fmaf(dz, w.y, gy);
    }
    const float sg0 = (gx > 0.f) ? 1.f : ((gx < 0.f) ? -1.f : 0.f);
    const float sg1 = (gy > 0.f) ? 1.f : ((gy < 0.f) ? -1.f : 0.f);
    const float p0 = pooledS[2*t], p1 = pooledS[2*t+1];
    float dd0 = fminf(fmaxf((xaS[2*t]   - 0.01f*sg0) - p0, -0.2f), 0.2f);
    float dd1 = fminf(fmaxf((xaS[2*t+1] - 0.01f*sg1) - p1, -0.2f), 0.2f);
    xaS[2*t]   = p0 + dd0;
    xaS[2*t+1] = p1 + dd1;
    __syncthreads();
  }
  if (t == 0) scores[b] = sig_last;
}

// ---------- tail outputs ----------
__global__ __launch_bounds__(64) void k_finalize(
    const float* __restrict__ scores, float* __restrict__ out)
{
  const int t = threadIdx.x;
  const float s = scores[t];
  out[X_ELEMS + t] = s;                    // worst_score
  out[X_ELEMS + nB + t] = 1.0f - s;        // cert_score
  float m = s;
  for (int o = 32; o > 0; o >>= 1) m = fminf(m, __shfl_xor(m, o, 64));
  if (t == 0) out[X_ELEMS + 2 * nB] = (m < 0.1f) ? 1.0f : 0.0f;  // violated
}

extern "C" void kernel_launch(void* const* d_in, const int* in_sizes, int n_in,
                              void* d_out, int out_size, void* d_ws, size_t ws_size,
                              hipStream_t stream) {
  const float* x  = (const float*)d_in[0];
  const float* W1 = (const float*)d_in[1];
  const float* b1 = (const float*)d_in[2];
  const float* W2 = (const float*)d_in[3];
  const float* b2 = (const float*)d_in[4];
  float* out = (float*)d_out;
  float* ws = (float*)d_ws;

  constexpr size_t PMEAN_ELEMS  = (size_t)nB * NT * nD;   // 2,097,152
  constexpr size_t POOLED_ELEMS = (size_t)nB * nD;        // 131,072
  constexpr size_t W1T_ELEMS    = (size_t)nD * nH;        // 262,144
  const size_t primary_bytes =
      (PMEAN_ELEMS + W1T_ELEMS + nB) * sizeof(float) + nB * sizeof(int);

  if (ws_size >= primary_bytes) {
    float* pmean  = ws;
    float* w1t    = ws + PMEAN_ELEMS;
    float* scores = w1t + W1T_ELEMS;
    int*   ctr    = (int*)(scores + nB);

    k_zero<<<1, 256, 0, stream>>>((float*)ctr, nB);          // reset gate
    k_transpose<<<dim3(32, 2), 256, 0, stream>>>(W1, w1t);
    k_fused<<<nB * NT + nB, 256, 0, stream>>>(x, out, W1, w1t, b1, W2, b2,
                                              pmean, scores, ctr);
    k_finalize<<<1, 64, 0, stream>>>(scores, out);
  } else {
    float* pooled = ws;
    float* w1t    = ws + POOLED_ELEMS;
    float* scores = w1t + W1T_ELEMS;

    k_zero<<<(int)(POOLED_ELEMS + 255) / 256, 256, 0, stream>>>(pooled,
                                                                (int)POOLED_ELEMS);
    k_copy_mean_atomic<<<nB * NT, 256, 0, stream>>>(x, out, pooled);
    k_transpose<<<dim3(32, 2), 256, 0, stream>>>(W1, w1t);
    k_pgd<<<nB, 1024, 0, stream>>>(W1, w1t, b1, W2, b2, pooled, scores);
    k_finalize<<<1, 64, 0, stream>>>(scores, out);
  }
}

// Round 5
// 355.936 us; speedup vs baseline: 1.9248x; 1.9248x over previous
//
#include <hip/hip_runtime.h>
#include <hip/hip_bf16.h>
#include <stdint.h>

#define DEV __device__ __forceinline__

typedef float f32x4 __attribute__((ext_vector_type(4)));

constexpr int nB = 64;
constexpr int nL = 1024;
constexpr int nD = 2048;
constexpr int nH = 128;

constexpr int NT = 16;          // L tiles for mean
constexpr int LT = nL / NT;     // 64 rows per tile

constexpr size_t X_ELEMS = (size_t)nB * (size_t)nL * (size_t)nD;  // 134217728

// ---------- math helpers (match JAX/XLA fp32 semantics closely) ----------
DEV float gelu_f(float x) {
  return 0.5f * x * (1.0f + erff(x * 0.7071067811865476f));
}
DEV float gelu_grad_f(float x) {
  return 0.5f * (1.0f + erff(x * 0.7071067811865476f))
       + x * 0.3989422804014327f * expf(-0.5f * x * x);
}
DEV float sigmoid_f(float x) { return 1.0f / (1.0f + expf(-x)); }

DEV uint32_t rotl32(uint32_t v, int r) { return (v << r) | (v >> (32 - r)); }

DEV float bf2f(uint16_t u) { return __uint_as_float(((uint32_t)u) << 16); }

// Threefry-2x32 with key (0,1)  == jax.random.key(1)
DEV void threefry_key01(uint32_t& x0, uint32_t& x1) {
  const uint32_t ks0 = 0u, ks1 = 1u, ks2 = 0x1BD11BDAu ^ 0u ^ 1u;
  x0 += ks0; x1 += ks1;
#define TF_RND(r) { x0 += x1; x1 = rotl32(x1, (r)); x1 ^= x0; }
  TF_RND(13) TF_RND(15) TF_RND(26) TF_RND(6)
  x0 += ks1; x1 += ks2 + 1u;
  TF_RND(17) TF_RND(29) TF_RND(16) TF_RND(24)
  x0 += ks2; x1 += ks0 + 2u;
  TF_RND(13) TF_RND(15) TF_RND(26) TF_RND(6)
  x0 += ks0; x1 += ks1 + 3u;
  TF_RND(17) TF_RND(29) TF_RND(16) TF_RND(24)
  x0 += ks1; x1 += ks2 + 4u;
  TF_RND(13) TF_RND(15) TF_RND(26) TF_RND(6)
  x0 += ks2; x1 += ks0 + 5u;
#undef TF_RND
}

// XLA ErfInv32 (Giles single-precision polynomial)
DEV float erfinv_f32(float x) {
  float w = -log1pf(-x * x);
  float p;
  if (w < 5.0f) {
    w -= 2.5f;
    p = 2.81022636e-08f;
    p = fmaf(p, w, 3.43273939e-07f);
    p = fmaf(p, w, -3.5233877e-06f);
    p = fmaf(p, w, -4.39150654e-06f);
    p = fmaf(p, w, 0.00021858087f);
    p = fmaf(p, w, -0.00125372503f);
    p = fmaf(p, w, -0.00417768164f);
    p = fmaf(p, w, 0.246640727f);
    p = fmaf(p, w, 1.50140941f);
  } else {
    w = sqrtf(w) - 3.0f;
    p = -0.000200214257f;
    p = fmaf(p, w, 0.000100950558f);
    p = fmaf(p, w, 0.00134934322f);
    p = fmaf(p, w, -0.00367342844f);
    p = fmaf(p, w, 0.00573950773f);
    p = fmaf(p, w, -0.0076224613f);
    p = fmaf(p, w, 0.00943887047f);
    p = fmaf(p, w, 1.00167406f);
    p = fmaf(p, w, 2.83297682f);
  }
  return p * x;
}

// jax.random.normal(key(1), (64,2048), f32), element i of row-major flat array
DEV float jax_normal_key1(int i) {
  const uint32_t j = (uint32_t)(i & 0xFFFF);
  uint32_t x0 = j, x1 = j + 65536u;
  threefry_key01(x0, x1);
  const uint32_t bits = (i < 65536) ? x0 : x1;
  const float u01 = __uint_as_float((bits >> 9) | 0x3F800000u) - 1.0f;
  const float lo = __uint_as_float(0xBF7FFFFFu);   // nextafter(-1,0)
  float v = u01 * 2.0f + lo;
  v = fmaxf(lo, v);
  return 1.4142135623730951f * erfinv_f32(v);
}

// ---------- K1: fused copy x->out + deterministic partial mean ----------
// 2-row unroll: 4 float4 loads in flight per thread before stores (2x the
// in-flight bytes of the round-2 version, which sat at ~BDP).
__global__ __launch_bounds__(256) void k_copy_mean(
    const float* __restrict__ x, float* __restrict__ out,
    float* __restrict__ pmean)
{
  const int blk = blockIdx.x;            // = b*16 + tile
  const int t = threadIdx.x;
  const size_t base = (size_t)blk * LT * nD;
  const size_t o0 = (size_t)4 * t;       // d in [0,1024)
  const size_t o1 = 1024 + (size_t)4 * t;
  f32x4 a0 = {0.f, 0.f, 0.f, 0.f};
  f32x4 a1 = {0.f, 0.f, 0.f, 0.f};
  for (int l = 0; l < LT; l += 2) {
    const size_t r0 = base + (size_t)l * nD;
    const size_t r1 = r0 + nD;
    const f32x4 v0 = *reinterpret_cast<const f32x4*>(x + r0 + o0);
    const f32x4 v1 = *reinterpret_cast<const f32x4*>(x + r0 + o1);
    const f32x4 u0 = *reinterpret_cast<const f32x4*>(x + r1 + o0);
    const f32x4 u1 = *reinterpret_cast<const f32x4*>(x + r1 + o1);
    *reinterpret_cast<f32x4*>(out + r0 + o0) = v0;
    *reinterpret_cast<f32x4*>(out + r0 + o1) = v1;
    *reinterpret_cast<f32x4*>(out + r1 + o0) = u0;
    *reinterpret_cast<f32x4*>(out + r1 + o1) = u1;
    a0 += v0; a1 += v1;     // row l first, then row l+1: keeps the
    a0 += u0; a1 += u1;     // sequential-order sum of rounds 1-2
  }
  float* pm = pmean + (size_t)blk * nD;
  *reinterpret_cast<f32x4*>(pm + o0) = a0;
  *reinterpret_cast<f32x4*>(pm + o1) = a1;
}

// fallback when ws is small: atomic accumulate directly into pooled
__global__ __launch_bounds__(256) void k_copy_mean_atomic(
    const float* __restrict__ x, float* __restrict__ out,
    float* __restrict__ pooled)
{
  const int blk = blockIdx.x;
  const int b = blk >> 4;
  const int t = threadIdx.x;
  const size_t base = (size_t)blk * LT * nD;
  const size_t o0 = (size_t)4 * t;
  const size_t o1 = 1024 + (size_t)4 * t;
  f32x4 a0 = {0.f, 0.f, 0.f, 0.f};
  f32x4 a1 = {0.f, 0.f, 0.f, 0.f};
  for (int l = 0; l < LT; ++l) {
    const size_t r = base + (size_t)l * nD;
    const f32x4 v0 = *reinterpret_cast<const f32x4*>(x + r + o0);
    const f32x4 v1 = *reinterpret_cast<const f32x4*>(x + r + o1);
    *reinterpret_cast<f32x4*>(out + r + o0) = v0;
    *reinterpret_cast<f32x4*>(out + r + o1) = v1;
    a0 += v0; a1 += v1;
  }
  float* pp = pooled + (size_t)b * nD;
  const float sc = 1.0f / nL;
  atomicAdd(&pp[o0+0], a0.x*sc); atomicAdd(&pp[o0+1], a0.y*sc);
  atomicAdd(&pp[o0+2], a0.z*sc); atomicAdd(&pp[o0+3], a0.w*sc);
  atomicAdd(&pp[o1+0], a1.x*sc); atomicAdd(&pp[o1+1], a1.y*sc);
  atomicAdd(&pp[o1+2], a1.z*sc); atomicAdd(&pp[o1+3], a1.w*sc);
}

// ---------- K0: W1 [2048,128] f32 -> W1b [2048,128] bf16 + W1Tb [128,2048] bf16
__global__ __launch_bounds__(256) void k_prep(
    const float* __restrict__ W1, uint16_t* __restrict__ W1b,
    uint16_t* __restrict__ W1Tb)
{
  __shared__ float tile[64][65];
  const int bd = blockIdx.x;   // 0..31  (d block of 64)
  const int bh = blockIdx.y;   // 0..1   (h block of 64)
  const int t = threadIdx.x;
  const int j = t & 63;
  const int i0 = (t >> 6) * 16;
  for (int ii = 0; ii < 16; ++ii) {
    const int i = i0 + ii;
    const float v = W1[(size_t)(bd * 64 + i) * nH + bh * 64 + j];
    tile[i][j] = v;
    const __hip_bfloat16 hb = __float2bfloat16(v);
    W1b[(size_t)(bd * 64 + i) * nH + bh * 64 + j] =
        *reinterpret_cast<const uint16_t*>(&hb);
  }
  __syncthreads();
  for (int ii = 0; ii < 16; ++ii) {
    const int i = i0 + ii;     // i = h-local, j = d-local
    const __hip_bfloat16 hb = __float2bfloat16(tile[j][i]);
    W1Tb[(size_t)(bh * 64 + i) * nD + bd * 64 + j] =
        *reinterpret_cast<const uint16_t*>(&hb);
  }
}

// ---------- K2: whole PGD loop, one block per batch ----------
// Iterations 0..9 use bf16 weights (only sign(g) matters); the final
// scoring pass (it==10) uses fp32 W1 with round-2's exact arithmetic.
__global__ __launch_bounds__(1024) void k_pgd(
    const float* __restrict__ W1, const uint16_t* __restrict__ W1b,
    const uint16_t* __restrict__ W1Tb,
    const float* __restrict__ b1, const float* __restrict__ W2,
    const float* __restrict__ b2, const float* __restrict__ pmean,
    const float* __restrict__ pooledG, float* __restrict__ scores,
    const int from_partial)
{
  __shared__ float xaS[nD];
  __shared__ float pooledS[nD];
  __shared__ float redS[16][nH];
  __shared__ float dz1S[nH];
  __shared__ float red2[2];

  const int t = threadIdx.x;       // 0..1023
  const int b = blockIdx.x;        // 0..63

  // init: pooled + threefry noise -> xa0 (2 d per thread)
  {
    float2 pl;
    if (from_partial) {
      float2 s = make_float2(0.f, 0.f);
      for (int nt2 = 0; nt2 < NT; ++nt2) {
        const float2 v = *reinterpret_cast<const float2*>(
            &pmean[((size_t)(b * NT + nt2)) * nD + 2 * t]);
        s.x += v.x; s.y += v.y;
      }
      pl = make_float2(s.x * (1.0f / nL), s.y * (1.0f / nL));
    } else {
      pl = *reinterpret_cast<const float2*>(&pooledG[(size_t)b * nD + 2 * t]);
    }
    pooledS[2 * t]     = pl.x;
    pooledS[2 * t + 1] = pl.y;
    const int i0 = b * nD + 2 * t;
    xaS[2 * t]     = pl.x + 0.01f * jax_normal_key1(i0);
    xaS[2 * t + 1] = pl.y + 0.01f * jax_normal_key1(i0 + 1);
  }

  const float b1t = (t < nH) ? b1[t] : 0.f;
  const float w2t = (t < nH) ? W2[t] : 0.f;
  const float b2s = b2[0];

  __syncthreads();

  // bf16 fwd mapping: hp = h-pair 0..63, q = d-chunk 0..15 (128 d each)
  const int hp = t & 63;
  const int q  = t >> 6;
  const uint32_t* __restrict__ w1b2 =
      reinterpret_cast<const uint32_t*>(W1b);     // [d][h-pair]
  const uint32_t* __restrict__ w1tb2 =
      reinterpret_cast<const uint32_t*>(W1Tb);    // [h][d-pair]
  // fp32 final mapping: h = t&127, dq = t>>7 (256 d each)
  const int hf = t & (nH - 1);
  const int dq = t >> 7;

  float sig_last = 0.f;
  for (int it = 0; it <= 10; ++it) {
    float z1 = 0.f;
    if (it < 10) {
      // ---- bf16 forward: wave reads 256B/instr contiguous ----
      float accx = 0.f, accy = 0.f;
      const int dbase = q * 128;
      #pragma unroll 8
      for (int dd = 0; dd < 128; ++dd) {
        const float xv = xaS[dbase + dd];              // LDS broadcast
        const uint32_t w = w1b2[(size_t)(dbase + dd) * 64 + hp];
        accx = fmaf(xv, bf2f((uint16_t)(w & 0xFFFF)), accx);
        accy = fmaf(xv, bf2f((uint16_t)(w >> 16)), accy);
      }
      redS[q][2 * hp]     = accx;
      redS[q][2 * hp + 1] = accy;
      __syncthreads();
      if (t < nH) {
        #pragma unroll
        for (int q2 = 0; q2 < 16; ++q2) z1 += redS[q2][t];
        z1 += b1t;
      }
    } else {
      // ---- fp32 final forward: round-2 exact arithmetic ----
      float acc = 0.f;
      const float* __restrict__ w1p = W1 + (size_t)(dq * 256) * nH + hf;
      #pragma unroll 8
      for (int d = 0; d < 256; ++d)
        acc = fmaf(xaS[dq * 256 + d], w1p[(size_t)d * nH], acc);
      redS[dq][hf] = acc;
      __syncthreads();
      if (t < nH) {
        #pragma unroll
        for (int q2 = 0; q2 < 8; ++q2) z1 += redS[q2][t];
        z1 += b1t;
      }
    }

    if (t < nH) {
      float part = gelu_f(z1) * w2t;
      #pragma unroll
      for (int m = 1; m <= 32; m <<= 1) part += __shfl_xor(part, m, 64);
      if ((t & 63) == 0) red2[t >> 6] = part;
    }
    __syncthreads();

    const float sig = sigmoid_f(red2[0] + red2[1] + b2s);
    if (it == 10) { sig_last = sig; break; }

    if (t < nH) dz1S[t] = sig * (1.f - sig) * w2t * gelu_grad_f(z1);
    __syncthreads();

    // ---- bf16 backward: g = W1 . dz1; wave reads 256B/instr ----
    float gx = 0.f, gy = 0.f;
    #pragma unroll 8
    for (int h = 0; h < nH; ++h) {
      const float dz = dz1S[h];                        // LDS broadcast
      const uint32_t w = w1tb2[(size_t)h * 1024 + t];
      gx = fmaf(dz, bf2f((uint16_t)(w & 0xFFFF)), gx);
      gy = fmaf(dz, bf2f((uint16_t)(w >> 16)), gy);
    }
    const float sg0 = (gx > 0.f) ? 1.f : ((gx < 0.f) ? -1.f : 0.f);
    const float sg1 = (gy > 0.f) ? 1.f : ((gy < 0.f) ? -1.f : 0.f);
    const float p0 = pooledS[2 * t], p1 = pooledS[2 * t + 1];
    float d0 = fminf(fmaxf((xaS[2 * t]     - 0.01f * sg0) - p0, -0.2f), 0.2f);
    float d1 = fminf(fmaxf((xaS[2 * t + 1] - 0.01f * sg1) - p1, -0.2f), 0.2f);
    xaS[2 * t]     = p0 + d0;
    xaS[2 * t + 1] = p1 + d1;
    __syncthreads();
  }

  if (t == 0) scores[b] = sig_last;
}

// ---------- zero helper (graph-capture safe; fallback path only) ----------
__global__ __launch_bounds__(256) void k_zero(float* __restrict__ p, int n) {
  const int i = blockIdx.x * 256 + threadIdx.x;
  if (i < n) p[i] = 0.f;
}

// ---------- tail outputs ----------
__global__ __launch_bounds__(64) void k_finalize(
    const float* __restrict__ scores, float* __restrict__ out)
{
  const int t = threadIdx.x;  // 0..63
  const float s = scores[t];
  out[X_ELEMS + t] = s;                    // worst_score
  out[X_ELEMS + nB + t] = 1.0f - s;        // cert_score
  float m = s;
  for (int o = 32; o > 0; o >>= 1) m = fminf(m, __shfl_xor(m, o, 64));
  if (t == 0) out[X_ELEMS + 2 * nB] = (m < 0.1f) ? 1.0f : 0.0f;  // violated
}

extern "C" void kernel_launch(void* const* d_in, const int* in_sizes, int n_in,
                              void* d_out, int out_size, void* d_ws, size_t ws_size,
                              hipStream_t stream) {
  const float* x  = (const float*)d_in[0];
  const float* W1 = (const float*)d_in[1];
  const float* b1 = (const float*)d_in[2];
  const float* W2 = (const float*)d_in[3];
  const float* b2 = (const float*)d_in[4];
  float* out = (float*)d_out;
  float* ws = (float*)d_ws;

  constexpr size_t PMEAN_ELEMS  = (size_t)nB * NT * nD;   // 2,097,152 f32
  constexpr size_t POOLED_ELEMS = (size_t)nB * nD;        // 131,072 f32
  constexpr size_t W1_ELEMS     = (size_t)nD * nH;        // 262,144
  const size_t primary_bytes =
      PMEAN_ELEMS * 4 + W1_ELEMS * 2 * 2 + nB * 4;

  if (ws_size >= primary_bytes) {
    float*    pmean  = ws;
    uint16_t* w1b    = (uint16_t*)(ws + PMEAN_ELEMS);
    uint16_t* w1tb   = w1b + W1_ELEMS;
    float*    scores = (float*)(w1tb + W1_ELEMS);

    k_prep<<<dim3(32, 2), 256, 0, stream>>>(W1, w1b, w1tb);
    k_copy_mean<<<nB * NT, 256, 0, stream>>>(x, out, pmean);
    k_pgd<<<nB, 1024, 0, stream>>>(W1, w1b, w1tb, b1, W2, b2,
                                   pmean, nullptr, scores, 1);
    k_finalize<<<1, 64, 0, stream>>>(scores, out);
  } else {
    float*    pooled = ws;
    uint16_t* w1b    = (uint16_t*)(ws + POOLED_ELEMS);
    uint16_t* w1tb   = w1b + W1_ELEMS;
    float*    scores = (float*)(w1tb + W1_ELEMS);

    k_zero<<<(int)(POOLED_ELEMS + 255) / 256, 256, 0, stream>>>(
        pooled, (int)POOLED_ELEMS);
    k_prep<<<dim3(32, 2), 256, 0, stream>>>(W1, w1b, w1tb);
    k_copy_mean_atomic<<<nB * NT, 256, 0, stream>>>(x, out, pooled);
    k_pgd<<<nB, 1024, 0, stream>>>(W1, w1b, w1tb, b1, W2, b2,
                                   nullptr, pooled, scores, 0);
    k_finalize<<<1, 64, 0, stream>>>(scores, out);
  }
}